// Round 7
// baseline (298.496 us; speedup 1.0000x reference)
//
#include <hip/hip_runtime.h>
#include <hip/hip_bf16.h>
#include <cstdint>

#define T_TOK 8192
#define HID   1024
#define NE    9      // 8 routed experts + 1 shared
#define ISZ   512
#define RBASE 18432  // routed slot space: 16384 + 8*256 pad; shared rows at [RBASE, RBASE+8192)
#define NSLOT (RBASE + T_TOK)

#define BM 256
#define BN 256
#define BK 32
#define NROWB (NSLOT / BM)   // 104

typedef unsigned short u16;
typedef unsigned int   u32;
typedef __attribute__((ext_vector_type(8))) short short8;
typedef __attribute__((ext_vector_type(4))) float f32x4;

__device__ __forceinline__ u16 f2bf(float f) {
  u32 u = __builtin_bit_cast(u32, f);
  return (u16)((u + 0x7fffu + ((u >> 16) & 1u)) >> 16);
}
__device__ __forceinline__ float bf2f(u16 v) {
  return __builtin_bit_cast(float, (u32)v << 16);
}

#define STAGE(gp, lp) __builtin_amdgcn_global_load_lds( \
    (__attribute__((address_space(1))) u32*)(gp),       \
    (__attribute__((address_space(3))) u32*)(lp), 16, 0, 0)

// ---------------- weight conversions ----------------
__global__ void k_cvt_wgup(const float* __restrict__ wexp, const float* __restrict__ wsh,
                           u16* __restrict__ dst) {
  __shared__ float tile[32][33];
  const int e = blockIdx.z;
  const float* src = (e < 8) ? (wexp + (size_t)e * HID * 1024) : wsh;
  const int c0 = blockIdx.x * 32, h0 = blockIdx.y * 32;
  const int tx = threadIdx.x, ty = threadIdx.y;
  for (int i = ty; i < 32; i += 8)
    tile[i][tx] = src[(size_t)(h0 + i) * 1024 + c0 + tx];   // tile[h_loc][c_loc]
  __syncthreads();
  for (int j = ty; j < 32; j += 8) {
    int c = c0 + j;
    int i = (c < 512) ? c : (c - 512);
    int colp = ((i >> 4) * 32) + ((c < 512) ? 0 : 16) + (i & 15);
    dst[((size_t)e * 1024 + colp) * HID + h0 + tx] = f2bf(tile[tx][j]);
  }
}

__global__ void k_cvt_wdown(const float* __restrict__ wexp, const float* __restrict__ wsh,
                            u16* __restrict__ dst) {
  __shared__ float tile[32][33];
  const int e = blockIdx.z;
  const float* src = (e < 8) ? (wexp + (size_t)e * ISZ * HID) : wsh;
  const int h0 = blockIdx.x * 32, i0 = blockIdx.y * 32;
  const int tx = threadIdx.x, ty = threadIdx.y;
  for (int a = ty; a < 32; a += 8)
    tile[a][tx] = src[(size_t)(i0 + a) * HID + h0 + tx];    // tile[i_loc][h_loc]
  __syncthreads();
  for (int j = ty; j < 32; j += 8)
    dst[((size_t)e * HID + h0 + j) * ISZ + i0 + tx] = f2bf(tile[tx][j]);
}

// ---------------- router (fused x->bf16 conversion), no atomics ----------------
__global__ __launch_bounds__(256) void k_router(
    const float* __restrict__ x, const float* __restrict__ wg,
    u16* __restrict__ xb, int* __restrict__ eidx, float2* __restrict__ wts) {
  const int t = blockIdx.x * 4 + (threadIdx.x >> 6);
  const int l = threadIdx.x & 63;
  float a[8] = {0, 0, 0, 0, 0, 0, 0, 0};
  const float* xr = x + (size_t)t * HID;
  u16* xbr = xb + (size_t)t * HID;
#pragma unroll
  for (int j = 0; j < HID / 64; ++j) {
    const int h = j * 64 + l;
    const float xv = xr[h];
    xbr[h] = f2bf(xv);
    const float4 w0 = *(const float4*)&wg[h * 8];
    const float4 w1 = *(const float4*)&wg[h * 8 + 4];
    a[0] += xv * w0.x; a[1] += xv * w0.y; a[2] += xv * w0.z; a[3] += xv * w0.w;
    a[4] += xv * w1.x; a[5] += xv * w1.y; a[6] += xv * w1.z; a[7] += xv * w1.w;
  }
#pragma unroll
  for (int off = 32; off >= 1; off >>= 1) {
#pragma unroll
    for (int e2 = 0; e2 < 8; ++e2) a[e2] += __shfl_xor(a[e2], off);
  }
  if (l == 0) {
    int ia = 0;
#pragma unroll
    for (int e2 = 1; e2 < 8; ++e2) if (a[e2] > a[ia]) ia = e2;
    int ib = (ia == 0) ? 1 : 0;
#pragma unroll
    for (int e2 = 0; e2 < 8; ++e2) if (e2 != ia && a[e2] > a[ib]) ib = e2;
    float wa = 1.f / (1.f + expf(a[ib] - a[ia]));  // renormalized softmax top-2
    eidx[t] = ia | (ib << 8);
    wts[t] = make_float2(wa, 1.f - wa);
  }
}

// ---------------- deterministic counting scatter (256-aligned segments) --------
__global__ __launch_bounds__(512) void k_scatter(
    const int* __restrict__ eidx, const float2* __restrict__ wts,
    int* __restrict__ btok, float* __restrict__ bw, int* __restrict__ slotmap,
    int* __restrict__ seg, int* __restrict__ segcnt) {
  __shared__ int cnt_s[8];
  __shared__ int goff_s[9];
  const int e = threadIdx.x >> 6;
  const int l = threadIdx.x & 63;

  int c1 = 0;
  for (int c = 0; c < T_TOK / 64; ++c) {
    int v = eidx[c * 64 + l];
    c1 += __popcll(__ballot((v & 255) == e)) + __popcll(__ballot(((v >> 8) & 255) == e));
  }
  if (l == 0) cnt_s[e] = c1;
  __syncthreads();
  if (threadIdx.x == 0) {
    int off = 0;
    for (int k = 0; k < 8; ++k) { goff_s[k] = off; off += (cnt_s[k] + 255) & ~255; }
    goff_s[8] = off;
  }
  __syncthreads();
  const int base0 = goff_s[e];
  const int cnt_e = cnt_s[e];
  const unsigned long long below = (l == 63) ? ~0ull >> 1 : ((1ull << l) - 1);

  int base = base0;
  for (int c = 0; c < T_TOK / 64; ++c) {
    const int t = c * 64 + l;
    const int v = eidx[t];
    const float2 wv = wts[t];
    const unsigned long long ma = __ballot((v & 255) == e);
    const unsigned long long mb = __ballot(((v >> 8) & 255) == e);
    if ((v & 255) == e) {
      int s = base + __popcll(ma & below);
      btok[s] = t; bw[s] = wv.x; slotmap[2 * t] = s;
    }
    if (((v >> 8) & 255) == e) {
      int s = base + __popcll(ma) + __popcll(mb & below);
      btok[s] = t; bw[s] = wv.y; slotmap[2 * t + 1] = s;
    }
    base += __popcll(ma) + __popcll(mb);
  }
  for (int p = cnt_e + l; p < ((cnt_e + 255) & ~255); p += 64) {
    btok[base0 + p] = 0; bw[base0 + p] = 0.f;
  }
  if (threadIdx.x < 9) seg[threadIdx.x] = goff_s[threadIdx.x];
  if (threadIdx.x < 8) segcnt[threadIdx.x] = cnt_s[threadIdx.x];
}

// ---------------- gather: xg[slot] = xb[btok[slot]]  (routed slots only) --------
// Makes GEMM1's A operand fully contiguous. Rows are 2KB contiguous -> coalesced.
__global__ __launch_bounds__(256) void k_gather(
    const u16* __restrict__ xb, const int* __restrict__ btok,
    const int* __restrict__ seg, u16* __restrict__ xg) {
  const int idx = blockIdx.x * 256 + threadIdx.x;
  const int slot = idx >> 7;            // 128 threads per row (16B each)
  if (slot >= seg[8]) return;           // beyond last routed segment: never read
  const int c = (idx & 127) << 3;
  const int t = btok[slot];
  *(short8*)(xg + (size_t)slot * HID + c) =
      *(const short8*)(xb + (size_t)t * HID + c);
}

// ---------------- segment lookup ----------------
__device__ __forceinline__ bool seg_lookup(const int* __restrict__ seg,
                                           const int* __restrict__ segcnt,
                                           int brow, int& e) {
  if (brow >= RBASE) { e = 8; return true; }
  if (brow >= seg[8]) return false;
  e = 0;
#pragma unroll
  for (int k = 1; k < 8; ++k) if (brow >= seg[k]) e = k;
  return brow < seg[e] + segcnt[e];
}

// =================================================================================
// 256x256 tile, BK=32, 4-slot rotating LDS pipeline, counted vmcnt(8), swizzled LDS
// 8 waves: wave w -> rows (w>>2)*128..+128, cols (w&3)*64..+64 of the tile.
// LDS swizzle: 16B chunk q of row r holds global chunk q ^ (r&3)  (both sides).
// =================================================================================

// ---------------- GEMM1: act[slot] = silu(g)*u * w  (A now contiguous) ----------
__global__ __launch_bounds__(512, 1) void k_gemm_gu(
    const u16* __restrict__ xg,     // [RBASE][H] bf16 (pre-gathered routed rows)
    const u16* __restrict__ xb,     // [T][H] bf16 (shared-expert rows)
    const u16* __restrict__ wgupT,  // [NE][1024][H] bf16 (B^T, gate/up interleaved)
    const int* __restrict__ seg, const int* __restrict__ segcnt,
    const float* __restrict__ bw,
    u16* __restrict__ act)          // [NSLOT][ISZ] bf16 (pre-scaled)
{
  const int bid = blockIdx.x;
  const int brow = (bid % NROWB) * BM;
  const int bcol = (bid / NROWB) * BN;
  int e;
  if (!seg_lookup(seg, segcnt, brow, e)) return;

  __shared__ __align__(16) u16 As[4 * 8192];   // 64 KB: 4 slots x [256][32]
  __shared__ __align__(16) u16 Bs[4 * 8192];   // 64 KB
  __shared__ float cws[BM];

  const int tid = threadIdx.x;
  const int w = tid >> 6, l = tid & 63;
  const int wr = w >> 2, wc = w & 3;
  const int fr = l & 15, fg = l >> 4;

  if (tid < BM) cws[tid] = (e < 8) ? bw[brow + tid] : 1.f;

  // staging: thread covers tile rows r0 = tid>>2 and r1 = r0+128, 16B chunk (tid&3)
  const int r0 = tid >> 2, r1 = r0 + 128;
  const int swz = 8 * ((tid & 3) ^ (r0 & 3));   // pre-swizzled source chunk (elements)
  const u16* Abase = (e < 8) ? (xg + (size_t)brow * HID)
                             : (xb + (size_t)(brow - RBASE) * HID);
  const u16* gA0 = Abase + (size_t)r0 * HID + swz;
  const u16* gA1 = Abase + (size_t)r1 * HID + swz;
  const u16* gB0 = wgupT + ((size_t)e * 1024 + bcol + r0) * HID + swz;
  const u16* gB1 = wgupT + ((size_t)e * 1024 + bcol + r1) * HID + swz;
  u16* const lA = As + w * 512;                 // wave-uniform LDS base (+lane*16B HW)
  u16* const lB = Bs + w * 512;

#define STG1(kt_t, s) do {                         \
    STAGE(gA0 + (kt_t) * BK, lA + (s) * 8192);     \
    STAGE(gA1 + (kt_t) * BK, lA + (s) * 8192 + 4096); \
    STAGE(gB0 + (kt_t) * BK, lB + (s) * 8192);     \
    STAGE(gB1 + (kt_t) * BK, lB + (s) * 8192 + 4096); } while (0)

  f32x4 acc[8][4];
#pragma unroll
  for (int m = 0; m < 8; ++m)
#pragma unroll
    for (int n = 0; n < 4; ++n) acc[m][n] = (f32x4){0.f, 0.f, 0.f, 0.f};

  STG1(0, 0); STG1(1, 1); STG1(2, 2);

  const int xs = (fg ^ (fr & 3)) * 8;           // swizzled chunk on read side
  const int aB = (wr * 128 + fr) * 32 + xs;
  const int bB = (wc * 64 + fr) * 32 + xs;

  const int NKT = HID / BK;   // 32
  for (int kt = 0; kt < NKT; ++kt) {
    if (kt < NKT - 2)       asm volatile("s_waitcnt vmcnt(8)" ::: "memory");
    else if (kt == NKT - 2) asm volatile("s_waitcnt vmcnt(4)" ::: "memory");
    else                    asm volatile("s_waitcnt vmcnt(0)" ::: "memory");
    __builtin_amdgcn_s_barrier();
    __builtin_amdgcn_sched_barrier(0);
    const int s = kt & 3;
    if (kt + 3 < NKT) STG1(kt + 3, (kt + 3) & 3);
    short8 af[8], bf_[4];
#pragma unroll
    for (int m = 0; m < 8; ++m)
      af[m] = *(const short8*)&As[s * 8192 + aB + m * 512];
#pragma unroll
    for (int n = 0; n < 4; ++n)
      bf_[n] = *(const short8*)&Bs[s * 8192 + bB + n * 512];
    __builtin_amdgcn_s_setprio(1);
#pragma unroll
    for (int m = 0; m < 8; ++m)
#pragma unroll
      for (int n = 0; n < 4; ++n)
        acc[m][n] = __builtin_amdgcn_mfma_f32_16x16x32_bf16(af[m], bf_[n], acc[m][n], 0, 0, 0);
    __builtin_amdgcn_s_setprio(0);
  }
#undef STG1

  // epilogue: pair adjacent 16-col fragments (gate, up), silu*up*w -> act bf16
#pragma unroll
  for (int m = 0; m < 8; ++m) {
#pragma unroll
    for (int p = 0; p < 2; ++p) {
      f32x4 g = acc[m][2 * p], u = acc[m][2 * p + 1];
      const int col = ((bcol + wc * 64) >> 1) + p * 16 + fr;
#pragma unroll
      for (int r = 0; r < 4; ++r) {
        const int row_l = wr * 128 + m * 16 + fg * 4 + r;
        float gate = g[r];
        float sv = gate / (1.f + __expf(-gate));
        act[(size_t)(brow + row_l) * ISZ + col] = f2bf(sv * u[r] * cws[row_l]);
      }
    }
  }
}

// ---------------- GEMM2 (unified): tmp[slot] = act[slot] @ wdT[e] ----------------
__global__ __launch_bounds__(512, 1) void k_gemm_down(
    const u16* __restrict__ act, const u16* __restrict__ wdT,
    const int* __restrict__ seg, const int* __restrict__ segcnt,
    u16* __restrict__ tmp) {
  const int bid = blockIdx.x;
  const int brow = (bid % NROWB) * BM;
  const int bcol = (bid / NROWB) * BN;
  int e;
  if (!seg_lookup(seg, segcnt, brow, e)) return;

  __shared__ __align__(16) u16 As[4 * 8192];
  __shared__ __align__(16) u16 Bs[4 * 8192];

  const int tid = threadIdx.x;
  const int w = tid >> 6, l = tid & 63;
  const int wr = w >> 2, wc = w & 3;
  const int fr = l & 15, fg = l >> 4;

  const int r0 = tid >> 2, r1 = r0 + 128;
  const int swz = 8 * ((tid & 3) ^ (r0 & 3));
  const u16* gA0 = act + (size_t)(brow + r0) * ISZ + swz;
  const u16* gA1 = act + (size_t)(brow + r1) * ISZ + swz;
  const u16* gB0 = wdT + ((size_t)e * HID + bcol + r0) * ISZ + swz;
  const u16* gB1 = wdT + ((size_t)e * HID + bcol + r1) * ISZ + swz;
  u16* const lA = As + w * 512;
  u16* const lB = Bs + w * 512;

#define STG2(kt_t, s) do {                         \
    STAGE(gA0 + (kt_t) * BK, lA + (s) * 8192);     \
    STAGE(gA1 + (kt_t) * BK, lA + (s) * 8192 + 4096); \
    STAGE(gB0 + (kt_t) * BK, lB + (s) * 8192);     \
    STAGE(gB1 + (kt_t) * BK, lB + (s) * 8192 + 4096); } while (0)

  f32x4 acc[8][4];
#pragma unroll
  for (int m = 0; m < 8; ++m)
#pragma unroll
    for (int n = 0; n < 4; ++n) acc[m][n] = (f32x4){0.f, 0.f, 0.f, 0.f};

  STG2(0, 0); STG2(1, 1); STG2(2, 2);

  const int xs = (fg ^ (fr & 3)) * 8;
  const int aB = (wr * 128 + fr) * 32 + xs;
  const int bB = (wc * 64 + fr) * 32 + xs;

  const int NKT = ISZ / BK;   // 16
  for (int kt = 0; kt < NKT; ++kt) {
    if (kt < NKT - 2)       asm volatile("s_waitcnt vmcnt(8)" ::: "memory");
    else if (kt == NKT - 2) asm volatile("s_waitcnt vmcnt(4)" ::: "memory");
    else                    asm volatile("s_waitcnt vmcnt(0)" ::: "memory");
    __builtin_amdgcn_s_barrier();
    __builtin_amdgcn_sched_barrier(0);
    const int s = kt & 3;
    if (kt + 3 < NKT) STG2(kt + 3, (kt + 3) & 3);
    short8 af[8], bf_[4];
#pragma unroll
    for (int m = 0; m < 8; ++m)
      af[m] = *(const short8*)&As[s * 8192 + aB + m * 512];
#pragma unroll
    for (int n = 0; n < 4; ++n)
      bf_[n] = *(const short8*)&Bs[s * 8192 + bB + n * 512];
    __builtin_amdgcn_s_setprio(1);
#pragma unroll
    for (int m = 0; m < 8; ++m)
#pragma unroll
      for (int n = 0; n < 4; ++n)
        acc[m][n] = __builtin_amdgcn_mfma_f32_16x16x32_bf16(af[m], bf_[n], acc[m][n], 0, 0, 0);
    __builtin_amdgcn_s_setprio(0);
  }
#undef STG2

#pragma unroll
  for (int m = 0; m < 8; ++m) {
#pragma unroll
    for (int r = 0; r < 4; ++r) {
      const int row = brow + wr * 128 + m * 16 + fg * 4 + r;
#pragma unroll
      for (int n = 0; n < 4; ++n) {
        const int col = bcol + wc * 64 + n * 16 + fr;
        tmp[(size_t)row * HID + col] = f2bf(acc[m][n][r]);
      }
    }
  }
}

// ---------------- combine: out[t] = tmp[sh] + tmp[s0] + tmp[s1]  (pure write) ----
__global__ __launch_bounds__(256) void k_combine(
    const u16* __restrict__ tmp, const int* __restrict__ slotmap,
    float* __restrict__ out) {
  const int idx = blockIdx.x * 256 + threadIdx.x;
  const int t = idx >> 7;
  const int c = (idx & 127) << 3;
  const int s0 = slotmap[2 * t], s1 = slotmap[2 * t + 1];
  const short8 a = *(const short8*)(tmp + (size_t)s0 * HID + c);
  const short8 b = *(const short8*)(tmp + (size_t)s1 * HID + c);
  const short8 s = *(const short8*)(tmp + (size_t)(RBASE + t) * HID + c);
  float r[8];
#pragma unroll
  for (int j = 0; j < 8; ++j)
    r[j] = bf2f((u16)s[j]) + bf2f((u16)a[j]) + bf2f((u16)b[j]);
  float* po = out + (size_t)t * HID + c;
  *(float4*)po       = make_float4(r[0], r[1], r[2], r[3]);
  *(float4*)(po + 4) = make_float4(r[4], r[5], r[6], r[7]);
}

// ---------------- launch ----------------
extern "C" void kernel_launch(void* const* d_in, const int* in_sizes, int n_in,
                              void* d_out, int out_size, void* d_ws, size_t ws_size,
                              hipStream_t stream) {
  const float* x   = (const float*)d_in[0];
  const float* wg  = (const float*)d_in[1];
  const float* wgu = (const float*)d_in[2];
  const float* wdn = (const float*)d_in[3];
  const float* wsg = (const float*)d_in[4];
  const float* wsd = (const float*)d_in[5];
  float* out = (float*)d_out;

  char* ws = (char*)d_ws;
  u16* xb    = (u16*)ws;  ws += (size_t)T_TOK * HID * 2;
  u16* xg    = (u16*)ws;  ws += (size_t)RBASE * HID * 2;
  u16* wgupT = (u16*)ws;  ws += (size_t)NE * 1024 * HID * 2;
  u16* wdT   = (u16*)ws;  ws += (size_t)NE * HID * ISZ * 2;
  u16* actb  = (u16*)ws;  ws += (size_t)NSLOT * ISZ * 2;
  u16* tmp   = (u16*)ws;  ws += (size_t)NSLOT * HID * 2;
  int* eidx  = (int*)ws;  ws += (size_t)T_TOK * 4;
  float2* wt = (float2*)ws; ws += (size_t)T_TOK * 8;
  int* btok  = (int*)ws;  ws += (size_t)RBASE * 4;
  float* bwp = (float*)ws; ws += (size_t)RBASE * 4;
  int* smap  = (int*)ws;  ws += (size_t)2 * T_TOK * 4;
  int* seg   = (int*)ws;  ws += 16 * 4;
  int* segc  = (int*)ws;

  k_cvt_wgup<<<dim3(32, 32, NE), dim3(32, 8), 0, stream>>>(wgu, wsg, wgupT);
  k_cvt_wdown<<<dim3(32, 16, NE), dim3(32, 8), 0, stream>>>(wdn, wsd, wdT);
  k_router<<<T_TOK / 4, 256, 0, stream>>>(x, wg, xb, eidx, wt);
  k_scatter<<<1, 512, 0, stream>>>(eidx, wt, btok, bwp, smap, seg, segc);
  k_gather<<<(RBASE * 128) / 256, 256, 0, stream>>>(xb, btok, seg, xg);
  k_gemm_gu<<<NROWB * 4, 512, 0, stream>>>(
      xg, xb, wgupT, seg, segc, bwp, actb);
  k_gemm_down<<<NROWB * 4, 512, 0, stream>>>(actb, wdT, seg, segc, tmp);
  k_combine<<<(T_TOK * HID / 8) / 256, 256, 0, stream>>>(tmp, smap, out);
}

// Round 8
// 276.513 us; speedup vs baseline: 1.0795x; 1.0795x over previous
//
#include <hip/hip_runtime.h>
#include <hip/hip_bf16.h>
#include <cstdint>

#define T_TOK 8192
#define HID   1024
#define NE    9      // 8 routed experts + 1 shared
#define ISZ   512
#define RBASE 17408  // routed slot space: 16384 + 8*128 pad; shared rows at [RBASE, RBASE+8192)
#define NSLOT (RBASE + T_TOK)

#define BM 128
#define BN 128
#define BK 32
#define NROWB (NSLOT / BM)   // 200

typedef unsigned short u16;
typedef unsigned int   u32;
typedef __attribute__((ext_vector_type(8))) short short8;
typedef __attribute__((ext_vector_type(4))) float f32x4;

__device__ __forceinline__ u16 f2bf(float f) {
  u32 u = __builtin_bit_cast(u32, f);
  return (u16)((u + 0x7fffu + ((u >> 16) & 1u)) >> 16);
}
__device__ __forceinline__ float bf2f(u16 v) {
  return __builtin_bit_cast(float, (u32)v << 16);
}

#define STAGE(gp, lp) __builtin_amdgcn_global_load_lds( \
    (__attribute__((address_space(1))) u32*)(gp),       \
    (__attribute__((address_space(3))) u32*)(lp), 16, 0, 0)

// ---------------- weight conversions ----------------
__global__ void k_cvt_wgup(const float* __restrict__ wexp, const float* __restrict__ wsh,
                           u16* __restrict__ dst) {
  __shared__ float tile[32][33];
  const int e = blockIdx.z;
  const float* src = (e < 8) ? (wexp + (size_t)e * HID * 1024) : wsh;
  const int c0 = blockIdx.x * 32, h0 = blockIdx.y * 32;
  const int tx = threadIdx.x, ty = threadIdx.y;
  for (int i = ty; i < 32; i += 8)
    tile[i][tx] = src[(size_t)(h0 + i) * 1024 + c0 + tx];   // tile[h_loc][c_loc]
  __syncthreads();
  for (int j = ty; j < 32; j += 8) {
    int c = c0 + j;
    int i = (c < 512) ? c : (c - 512);
    int colp = ((i >> 4) * 32) + ((c < 512) ? 0 : 16) + (i & 15);
    dst[((size_t)e * 1024 + colp) * HID + h0 + tx] = f2bf(tile[tx][j]);
  }
}

__global__ void k_cvt_wdown(const float* __restrict__ wexp, const float* __restrict__ wsh,
                            u16* __restrict__ dst) {
  __shared__ float tile[32][33];
  const int e = blockIdx.z;
  const float* src = (e < 8) ? (wexp + (size_t)e * ISZ * HID) : wsh;
  const int h0 = blockIdx.x * 32, i0 = blockIdx.y * 32;
  const int tx = threadIdx.x, ty = threadIdx.y;
  for (int a = ty; a < 32; a += 8)
    tile[a][tx] = src[(size_t)(i0 + a) * HID + h0 + tx];    // tile[i_loc][h_loc]
  __syncthreads();
  for (int j = ty; j < 32; j += 8)
    dst[((size_t)e * HID + h0 + j) * ISZ + i0 + tx] = f2bf(tile[tx][j]);
}

// ---------------- router (vectorized float4 loads, fused x->bf16) ----------------
__global__ __launch_bounds__(256) void k_router(
    const float* __restrict__ x, const float* __restrict__ wg,
    u16* __restrict__ xb, int* __restrict__ eidx, float2* __restrict__ wts) {
  const int t = blockIdx.x * 4 + (threadIdx.x >> 6);
  const int l = threadIdx.x & 63;
  float a[8] = {0, 0, 0, 0, 0, 0, 0, 0};
  const float4* xr4 = (const float4*)(x + (size_t)t * HID);
  ushort4* xb4 = (ushort4*)(xb + (size_t)t * HID);
#pragma unroll
  for (int j = 0; j < 4; ++j) {
    const float4 v = xr4[j * 64 + l];
    ushort4 o;
    o.x = f2bf(v.x); o.y = f2bf(v.y); o.z = f2bf(v.z); o.w = f2bf(v.w);
    xb4[j * 64 + l] = o;
    const int h = (j * 64 + l) * 4;
    const float ev[4] = {v.x, v.y, v.z, v.w};
#pragma unroll
    for (int i = 0; i < 4; ++i) {
      const float4 w0 = *(const float4*)&wg[(h + i) * 8];
      const float4 w1 = *(const float4*)&wg[(h + i) * 8 + 4];
      a[0] += ev[i] * w0.x; a[1] += ev[i] * w0.y; a[2] += ev[i] * w0.z; a[3] += ev[i] * w0.w;
      a[4] += ev[i] * w1.x; a[5] += ev[i] * w1.y; a[6] += ev[i] * w1.z; a[7] += ev[i] * w1.w;
    }
  }
#pragma unroll
  for (int off = 32; off >= 1; off >>= 1) {
#pragma unroll
    for (int e2 = 0; e2 < 8; ++e2) a[e2] += __shfl_xor(a[e2], off);
  }
  if (l == 0) {
    int ia = 0;
#pragma unroll
    for (int e2 = 1; e2 < 8; ++e2) if (a[e2] > a[ia]) ia = e2;
    int ib = (ia == 0) ? 1 : 0;
#pragma unroll
    for (int e2 = 0; e2 < 8; ++e2) if (e2 != ia && a[e2] > a[ib]) ib = e2;
    float wa = 1.f / (1.f + expf(a[ib] - a[ia]));  // renormalized softmax top-2
    eidx[t] = ia | (ib << 8);
    wts[t] = make_float2(wa, 1.f - wa);
  }
}

// ---------------- deterministic counting scatter (128-aligned segments) --------
__global__ __launch_bounds__(512) void k_scatter(
    const int* __restrict__ eidx, const float2* __restrict__ wts,
    int* __restrict__ btok, float* __restrict__ bw, int* __restrict__ slotmap,
    int* __restrict__ seg, int* __restrict__ segcnt) {
  __shared__ int cnt_s[8];
  __shared__ int goff_s[9];
  const int e = threadIdx.x >> 6;
  const int l = threadIdx.x & 63;

  int c1 = 0;
  for (int c = 0; c < T_TOK / 64; ++c) {
    int v = eidx[c * 64 + l];
    c1 += __popcll(__ballot((v & 255) == e)) + __popcll(__ballot(((v >> 8) & 255) == e));
  }
  if (l == 0) cnt_s[e] = c1;
  __syncthreads();
  if (threadIdx.x == 0) {
    int off = 0;
    for (int k = 0; k < 8; ++k) { goff_s[k] = off; off += (cnt_s[k] + 127) & ~127; }
    goff_s[8] = off;
  }
  __syncthreads();
  const int base0 = goff_s[e];
  const int cnt_e = cnt_s[e];
  const unsigned long long below = (l == 63) ? ~0ull >> 1 : ((1ull << l) - 1);

  int base = base0;
  for (int c = 0; c < T_TOK / 64; ++c) {
    const int t = c * 64 + l;
    const int v = eidx[t];
    const float2 wv = wts[t];
    const unsigned long long ma = __ballot((v & 255) == e);
    const unsigned long long mb = __ballot(((v >> 8) & 255) == e);
    if ((v & 255) == e) {
      int s = base + __popcll(ma & below);
      btok[s] = t; bw[s] = wv.x; slotmap[2 * t] = s;
    }
    if (((v >> 8) & 255) == e) {
      int s = base + __popcll(ma) + __popcll(mb & below);
      btok[s] = t; bw[s] = wv.y; slotmap[2 * t + 1] = s;
    }
    base += __popcll(ma) + __popcll(mb);
  }
  for (int p = cnt_e + l; p < ((cnt_e + 127) & ~127); p += 64) {
    btok[base0 + p] = 0; bw[base0 + p] = 0.f;
  }
  if (threadIdx.x < 9) seg[threadIdx.x] = goff_s[threadIdx.x];
  if (threadIdx.x < 8) segcnt[threadIdx.x] = cnt_s[threadIdx.x];
}

// ---------------- segment lookup ----------------
__device__ __forceinline__ bool seg_lookup(const int* __restrict__ seg,
                                           const int* __restrict__ segcnt,
                                           int brow, int& e) {
  if (brow >= RBASE) { e = 8; return true; }
  if (brow >= seg[8]) return false;
  e = 0;
#pragma unroll
  for (int k = 1; k < 8; ++k) if (brow >= seg[k]) e = k;
  return brow < seg[e] + segcnt[e];
}

// =================================================================================
// 128x128 tile, 8 waves (per-wave 64x32 out: acc[4][2] = 32 AGPR -> 2 blocks/CU),
// 4-slot rotating LDS (64 KB), counted vmcnt(2) (never drained in steady state),
// stage tile k+2 during tile k, one barrier per K-tile, chunk^row&3 swizzle.
// =================================================================================

// ---------------- GEMM1: act[slot] = silu(g)*u * w  (A gathered by token) -------
__global__ __launch_bounds__(512) void k_gemm_gu(
    const u16* __restrict__ xb,     // [T][H] bf16
    const u16* __restrict__ wgupT,  // [NE][1024][H] bf16 (B^T, gate/up interleaved)
    const int* __restrict__ seg, const int* __restrict__ segcnt,
    const int* __restrict__ btok, const float* __restrict__ bw,
    u16* __restrict__ act)          // [NSLOT][ISZ] bf16 (pre-scaled)
{
  const int brow = blockIdx.x * BM;
  const int bcol = blockIdx.y * BN;
  int e;
  if (!seg_lookup(seg, segcnt, brow, e)) return;

  __shared__ __align__(16) u16 As[4 * 4096];   // 4 slots x [128][32]
  __shared__ __align__(16) u16 Bs[4 * 4096];
  __shared__ float cws[BM];

  const int tid = threadIdx.x;
  const int w = tid >> 6, l = tid & 63;
  const int wm = w >> 2, wc = w & 3;           // 2 x 4 wave grid
  const int fr = l & 15, fg = l >> 4;

  if (tid < BM) cws[tid] = (e < 8) ? bw[brow + tid] : 1.f;

  // staging: thread -> tile row r0 = tid>>2, phys 16B chunk tid&3 (content swizzled)
  const int r0 = tid >> 2;
  const int sc = ((tid & 3) ^ (r0 & 3)) * 8;   // pre-swizzled source offset (elems)
  const int gs = brow + r0;
  const int t0 = (e < 8) ? btok[gs] : (gs - RBASE);
  const u16* gA = xb + (size_t)t0 * HID + sc;
  const u16* gB = wgupT + ((size_t)e * 1024 + bcol + r0) * HID + sc;
  u16* const lA = As + w * 512;                // wave base: lanes fill +16B each
  u16* const lB = Bs + w * 512;

  f32x4 acc[4][2];
#pragma unroll
  for (int m = 0; m < 4; ++m)
#pragma unroll
    for (int n = 0; n < 2; ++n) acc[m][n] = (f32x4){0.f, 0.f, 0.f, 0.f};

  // prologue: stage tiles 0,1
  STAGE(gA, lA);            STAGE(gB, lB);
  STAGE(gA + BK, lA + 4096); STAGE(gB + BK, lB + 4096);

  const int xs = (fg ^ (fr & 3)) * 8;          // swizzled read chunk
  const int aO = (wm * 64 + fr) * 32 + xs;     // + m*512
  const int bO = (wc * 32 + fr) * 32 + xs;     // + n*512

  const int NKT = HID / BK;   // 32
  for (int kt = 0; kt < NKT; ++kt) {
    if (kt == NKT - 1) asm volatile("s_waitcnt vmcnt(0)" ::: "memory");
    else               asm volatile("s_waitcnt vmcnt(2)" ::: "memory");
    __builtin_amdgcn_s_barrier();
    if (kt + 2 < NKT) {                        // stage k+2 into slot (kt+2)&3
      const int o = ((kt + 2) & 3) * 4096;
      STAGE(gA + (kt + 2) * BK, lA + o);
      STAGE(gB + (kt + 2) * BK, lB + o);
    }
    const int s = (kt & 3) * 4096;
    short8 af[4], bf_[2];
#pragma unroll
    for (int m = 0; m < 4; ++m) af[m] = *(const short8*)&As[s + aO + m * 512];
#pragma unroll
    for (int n = 0; n < 2; ++n) bf_[n] = *(const short8*)&Bs[s + bO + n * 512];
    asm volatile("s_waitcnt lgkmcnt(0)" ::: "memory");
    __builtin_amdgcn_sched_barrier(0);
    __builtin_amdgcn_s_setprio(1);
#pragma unroll
    for (int m = 0; m < 4; ++m)
#pragma unroll
      for (int n = 0; n < 2; ++n)
        acc[m][n] = __builtin_amdgcn_mfma_f32_16x16x32_bf16(af[m], bf_[n], acc[m][n], 0, 0, 0);
    __builtin_amdgcn_s_setprio(0);
  }

  // epilogue: n=0 frag = gate, n=1 = up for intermediate chunk ic
  const int ic = (bcol + wc * 32) >> 5;
#pragma unroll
  for (int m = 0; m < 4; ++m) {
    f32x4 g = acc[m][0], u = acc[m][1];
    const int col = ic * 16 + fr;
#pragma unroll
    for (int r = 0; r < 4; ++r) {
      const int row_l = wm * 64 + m * 16 + fg * 4 + r;
      float gate = g[r];
      float sv = gate / (1.f + __expf(-gate));
      act[(size_t)(brow + row_l) * ISZ + col] = f2bf(sv * u[r] * cws[row_l]);
    }
  }
}

// ---------------- GEMM2 (unified): tmp[slot] = act[slot] @ wdT[e] ----------------
__global__ __launch_bounds__(512) void k_gemm_down(
    const u16* __restrict__ act, const u16* __restrict__ wdT,
    const int* __restrict__ seg, const int* __restrict__ segcnt,
    u16* __restrict__ tmp) {
  const int brow = blockIdx.x * BM;
  const int bcol = blockIdx.y * BN;
  int e;
  if (!seg_lookup(seg, segcnt, brow, e)) return;

  __shared__ __align__(16) u16 As[4 * 4096];
  __shared__ __align__(16) u16 Bs[4 * 4096];

  const int tid = threadIdx.x;
  const int w = tid >> 6, l = tid & 63;
  const int wm = w >> 2, wc = w & 3;
  const int fr = l & 15, fg = l >> 4;

  const int r0 = tid >> 2;
  const int sc = ((tid & 3) ^ (r0 & 3)) * 8;
  const u16* gA = act + (size_t)(brow + r0) * ISZ + sc;
  const u16* gB = wdT + ((size_t)e * HID + bcol + r0) * ISZ + sc;
  u16* const lA = As + w * 512;
  u16* const lB = Bs + w * 512;

  f32x4 acc[4][2];
#pragma unroll
  for (int m = 0; m < 4; ++m)
#pragma unroll
    for (int n = 0; n < 2; ++n) acc[m][n] = (f32x4){0.f, 0.f, 0.f, 0.f};

  STAGE(gA, lA);             STAGE(gB, lB);
  STAGE(gA + BK, lA + 4096); STAGE(gB + BK, lB + 4096);

  const int xs = (fg ^ (fr & 3)) * 8;
  const int aO = (wm * 64 + fr) * 32 + xs;
  const int bO = (wc * 32 + fr) * 32 + xs;

  const int NKT = ISZ / BK;   // 16
  for (int kt = 0; kt < NKT; ++kt) {
    if (kt == NKT - 1) asm volatile("s_waitcnt vmcnt(0)" ::: "memory");
    else               asm volatile("s_waitcnt vmcnt(2)" ::: "memory");
    __builtin_amdgcn_s_barrier();
    if (kt + 2 < NKT) {
      const int o = ((kt + 2) & 3) * 4096;
      STAGE(gA + (kt + 2) * BK, lA + o);
      STAGE(gB + (kt + 2) * BK, lB + o);
    }
    const int s = (kt & 3) * 4096;
    short8 af[4], bf_[2];
#pragma unroll
    for (int m = 0; m < 4; ++m) af[m] = *(const short8*)&As[s + aO + m * 512];
#pragma unroll
    for (int n = 0; n < 2; ++n) bf_[n] = *(const short8*)&Bs[s + bO + n * 512];
    asm volatile("s_waitcnt lgkmcnt(0)" ::: "memory");
    __builtin_amdgcn_sched_barrier(0);
    __builtin_amdgcn_s_setprio(1);
#pragma unroll
    for (int m = 0; m < 4; ++m)
#pragma unroll
      for (int n = 0; n < 2; ++n)
        acc[m][n] = __builtin_amdgcn_mfma_f32_16x16x32_bf16(af[m], bf_[n], acc[m][n], 0, 0, 0);
    __builtin_amdgcn_s_setprio(0);
  }

#pragma unroll
  for (int m = 0; m < 4; ++m) {
#pragma unroll
    for (int r = 0; r < 4; ++r) {
      const int row = brow + wm * 64 + m * 16 + fg * 4 + r;
#pragma unroll
      for (int n = 0; n < 2; ++n) {
        const int col = bcol + wc * 32 + n * 16 + fr;
        tmp[(size_t)row * HID + col] = f2bf(acc[m][n][r]);
      }
    }
  }
}

// ---------------- combine: out[t] = tmp[sh] + tmp[s0] + tmp[s1]  (pure write) ----
__global__ __launch_bounds__(256) void k_combine(
    const u16* __restrict__ tmp, const int* __restrict__ slotmap,
    float* __restrict__ out) {
  const int idx = blockIdx.x * 256 + threadIdx.x;
  const int t = idx >> 7;
  const int c = (idx & 127) << 3;
  const int s0 = slotmap[2 * t], s1 = slotmap[2 * t + 1];
  const short8 a = *(const short8*)(tmp + (size_t)s0 * HID + c);
  const short8 b = *(const short8*)(tmp + (size_t)s1 * HID + c);
  const short8 s = *(const short8*)(tmp + (size_t)(RBASE + t) * HID + c);
  float r[8];
#pragma unroll
  for (int j = 0; j < 8; ++j)
    r[j] = bf2f((u16)s[j]) + bf2f((u16)a[j]) + bf2f((u16)b[j]);
  float* po = out + (size_t)t * HID + c;
  *(float4*)po       = make_float4(r[0], r[1], r[2], r[3]);
  *(float4*)(po + 4) = make_float4(r[4], r[5], r[6], r[7]);
}

// ---------------- launch ----------------
extern "C" void kernel_launch(void* const* d_in, const int* in_sizes, int n_in,
                              void* d_out, int out_size, void* d_ws, size_t ws_size,
                              hipStream_t stream) {
  const float* x   = (const float*)d_in[0];
  const float* wg  = (const float*)d_in[1];
  const float* wgu = (const float*)d_in[2];
  const float* wdn = (const float*)d_in[3];
  const float* wsg = (const float*)d_in[4];
  const float* wsd = (const float*)d_in[5];
  float* out = (float*)d_out;

  char* ws = (char*)d_ws;
  u16* xb    = (u16*)ws;  ws += (size_t)T_TOK * HID * 2;
  u16* wgupT = (u16*)ws;  ws += (size_t)NE * 1024 * HID * 2;
  u16* wdT   = (u16*)ws;  ws += (size_t)NE * HID * ISZ * 2;
  u16* actb  = (u16*)ws;  ws += (size_t)NSLOT * ISZ * 2;
  u16* tmp   = (u16*)ws;  ws += (size_t)NSLOT * HID * 2;
  int* eidx  = (int*)ws;  ws += (size_t)T_TOK * 4;
  float2* wt = (float2*)ws; ws += (size_t)T_TOK * 8;
  int* btok  = (int*)ws;  ws += (size_t)RBASE * 4;
  float* bwp = (float*)ws; ws += (size_t)RBASE * 4;
  int* smap  = (int*)ws;  ws += (size_t)2 * T_TOK * 4;
  int* seg   = (int*)ws;  ws += 16 * 4;
  int* segc  = (int*)ws;

  k_cvt_wgup<<<dim3(32, 32, NE), dim3(32, 8), 0, stream>>>(wgu, wsg, wgupT);
  k_cvt_wdown<<<dim3(32, 16, NE), dim3(32, 8), 0, stream>>>(wdn, wsd, wdT);
  k_router<<<T_TOK / 4, 256, 0, stream>>>(x, wg, xb, eidx, wt);
  k_scatter<<<1, 512, 0, stream>>>(eidx, wt, btok, bwp, smap, seg, segc);
  k_gemm_gu<<<dim3(NROWB, 8), 512, 0, stream>>>(
      xb, wgupT, seg, segc, btok, bwp, actb);
  k_gemm_down<<<dim3(NROWB, 8), 512, 0, stream>>>(actb, wdT, seg, segc, tmp);
  k_combine<<<(T_TOK * HID / 8) / 256, 256, 0, stream>>>(tmp, smap, out);
}

// Round 9
// 246.420 us; speedup vs baseline: 1.2113x; 1.1221x over previous
//
#include <hip/hip_runtime.h>
#include <hip/hip_bf16.h>
#include <cstdint>

#define T_TOK 8192
#define HID   1024
#define NE    9      // 8 routed experts + 1 shared
#define ISZ   512
#define RBASE 18432  // routed slots: 16384 + 8*256 pad; shared rows at [RBASE, RBASE+8192)
#define NSLOT (RBASE + T_TOK)   // 26624

#define BM 256
#define BN 128
#define BK 64
#define NROWB (NSLOT / BM)      // 104

typedef unsigned short u16;
typedef unsigned int   u32;
typedef __attribute__((ext_vector_type(8))) short short8;
typedef __attribute__((ext_vector_type(4))) float f32x4;

__device__ __forceinline__ u16 f2bf(float f) {
  u32 u = __builtin_bit_cast(u32, f);
  return (u16)((u + 0x7fffu + ((u >> 16) & 1u)) >> 16);
}
__device__ __forceinline__ float bf2f(u16 v) {
  return __builtin_bit_cast(float, (u32)v << 16);
}

#define STAGE(gp, lp) __builtin_amdgcn_global_load_lds( \
    (__attribute__((address_space(1))) u32*)(gp),       \
    (__attribute__((address_space(3))) u32*)(lp), 16, 0, 0)

// ---------------- weight conversions ----------------
__global__ void k_cvt_wgup(const float* __restrict__ wexp, const float* __restrict__ wsh,
                           u16* __restrict__ dst) {
  __shared__ float tile[32][33];
  const int e = blockIdx.z;
  const float* src = (e < 8) ? (wexp + (size_t)e * HID * 1024) : wsh;
  const int c0 = blockIdx.x * 32, h0 = blockIdx.y * 32;
  const int tx = threadIdx.x, ty = threadIdx.y;
  for (int i = ty; i < 32; i += 8)
    tile[i][tx] = src[(size_t)(h0 + i) * 1024 + c0 + tx];
  __syncthreads();
  for (int j = ty; j < 32; j += 8) {
    int c = c0 + j;
    int i = (c < 512) ? c : (c - 512);
    int colp = ((i >> 4) * 32) + ((c < 512) ? 0 : 16) + (i & 15);
    dst[((size_t)e * 1024 + colp) * HID + h0 + tx] = f2bf(tile[tx][j]);
  }
}

__global__ void k_cvt_wdown(const float* __restrict__ wexp, const float* __restrict__ wsh,
                            u16* __restrict__ dst) {
  __shared__ float tile[32][33];
  const int e = blockIdx.z;
  const float* src = (e < 8) ? (wexp + (size_t)e * ISZ * HID) : wsh;
  const int h0 = blockIdx.x * 32, i0 = blockIdx.y * 32;
  const int tx = threadIdx.x, ty = threadIdx.y;
  for (int a = ty; a < 32; a += 8)
    tile[a][tx] = src[(size_t)(i0 + a) * HID + h0 + tx];
  __syncthreads();
  for (int j = ty; j < 32; j += 8)
    dst[((size_t)e * HID + h0 + j) * ISZ + i0 + tx] = f2bf(tile[tx][j]);
}

// ---------------- router (vectorized, fused x->bf16) ----------------
__global__ __launch_bounds__(256) void k_router(
    const float* __restrict__ x, const float* __restrict__ wg,
    u16* __restrict__ xb, int* __restrict__ eidx, float2* __restrict__ wts) {
  const int t = blockIdx.x * 4 + (threadIdx.x >> 6);
  const int l = threadIdx.x & 63;
  float a[8] = {0, 0, 0, 0, 0, 0, 0, 0};
  const float4* xr4 = (const float4*)(x + (size_t)t * HID);
  ushort4* xb4 = (ushort4*)(xb + (size_t)t * HID);
#pragma unroll
  for (int j = 0; j < 4; ++j) {
    const float4 v = xr4[j * 64 + l];
    ushort4 o;
    o.x = f2bf(v.x); o.y = f2bf(v.y); o.z = f2bf(v.z); o.w = f2bf(v.w);
    xb4[j * 64 + l] = o;
    const int h = (j * 64 + l) * 4;
    const float ev[4] = {v.x, v.y, v.z, v.w};
#pragma unroll
    for (int i = 0; i < 4; ++i) {
      const float4 w0 = *(const float4*)&wg[(h + i) * 8];
      const float4 w1 = *(const float4*)&wg[(h + i) * 8 + 4];
      a[0] += ev[i] * w0.x; a[1] += ev[i] * w0.y; a[2] += ev[i] * w0.z; a[3] += ev[i] * w0.w;
      a[4] += ev[i] * w1.x; a[5] += ev[i] * w1.y; a[6] += ev[i] * w1.z; a[7] += ev[i] * w1.w;
    }
  }
#pragma unroll
  for (int off = 32; off >= 1; off >>= 1) {
#pragma unroll
    for (int e2 = 0; e2 < 8; ++e2) a[e2] += __shfl_xor(a[e2], off);
  }
  if (l == 0) {
    int ia = 0;
#pragma unroll
    for (int e2 = 1; e2 < 8; ++e2) if (a[e2] > a[ia]) ia = e2;
    int ib = (ia == 0) ? 1 : 0;
#pragma unroll
    for (int e2 = 0; e2 < 8; ++e2) if (e2 != ia && a[e2] > a[ib]) ib = e2;
    float wa = 1.f / (1.f + expf(a[ib] - a[ia]));
    eidx[t] = ia | (ib << 8);
    wts[t] = make_float2(wa, 1.f - wa);
  }
}

// ---------------- deterministic counting scatter (256-aligned segments) --------
__global__ __launch_bounds__(512) void k_scatter(
    const int* __restrict__ eidx, int* __restrict__ btok, int* __restrict__ slotmap,
    int* __restrict__ seg, int* __restrict__ segcnt) {
  __shared__ int cnt_s[8];
  __shared__ int goff_s[9];
  const int e = threadIdx.x >> 6;
  const int l = threadIdx.x & 63;

  int c1 = 0;
  for (int c = 0; c < T_TOK / 64; ++c) {
    int v = eidx[c * 64 + l];
    c1 += __popcll(__ballot((v & 255) == e)) + __popcll(__ballot(((v >> 8) & 255) == e));
  }
  if (l == 0) cnt_s[e] = c1;
  __syncthreads();
  if (threadIdx.x == 0) {
    int off = 0;
    for (int k = 0; k < 8; ++k) { goff_s[k] = off; off += (cnt_s[k] + 255) & ~255; }
    goff_s[8] = off;
  }
  __syncthreads();
  const int base0 = goff_s[e];
  const int cnt_e = cnt_s[e];
  const unsigned long long below = (l == 63) ? ~0ull >> 1 : ((1ull << l) - 1);

  int base = base0;
  for (int c = 0; c < T_TOK / 64; ++c) {
    const int t = c * 64 + l;
    const int v = eidx[t];
    const unsigned long long ma = __ballot((v & 255) == e);
    const unsigned long long mb = __ballot(((v >> 8) & 255) == e);
    if ((v & 255) == e) {
      int s = base + __popcll(ma & below);
      btok[s] = t; slotmap[2 * t] = s;
    }
    if (((v >> 8) & 255) == e) {
      int s = base + __popcll(ma) + __popcll(mb & below);
      btok[s] = t; slotmap[2 * t + 1] = s;
    }
    base += __popcll(ma) + __popcll(mb);
  }
  for (int p = cnt_e + l; p < ((cnt_e + 255) & ~255); p += 64) btok[base0 + p] = 0;
  if (threadIdx.x < 9) seg[threadIdx.x] = goff_s[threadIdx.x];
  if (threadIdx.x < 8) segcnt[threadIdx.x] = cnt_s[threadIdx.x];
}

__device__ __forceinline__ bool seg_lookup(const int* __restrict__ seg,
                                           const int* __restrict__ segcnt,
                                           int brow, int& e) {
  if (brow >= RBASE) { e = 8; return true; }
  if (brow >= seg[8]) return false;
  e = 0;
#pragma unroll
  for (int k = 1; k < 8; ++k) if (brow >= seg[k]) e = k;
  return brow < seg[e] + segcnt[e];
}

// =================================================================================
// 8-phase pipelined GEMM: 256x128 tile, BK=64, 8 waves (4M x 2N, 64x64 each).
// LDS: A = 2 K-step buffers (32 KB each), B = 3-deep ring (16 KB each) = 112 KB.
// Stage A at distance 1 K-step, B at distance 2; per-K-step vmcnt(2) (never 0
// until the last step). Chunk swizzle q ^= row&7 on both stage-source and read.
// Phase = {ds_reads, stage} -> barrier -> lgkm(0) -> setprio(1) 8 MFMA -> barrier.
// =================================================================================

#define STAGE_A(kt) do { const int _d = ((kt) & 1) * 16384 + w * 512;   \
    STAGE(sA0 + (kt) * 64, As + _d);                                    \
    STAGE(sA1 + (kt) * 64, As + _d + 4096);                             \
    STAGE(sA2 + (kt) * 64, As + _d + 8192);                             \
    STAGE(sA3 + (kt) * 64, As + _d + 12288); } while (0)
#define STAGE_B(kt) do { const int _d = ((kt) % 3) * 8192 + w * 512;    \
    STAGE(sB0 + (kt) * 64, Bs + _d);                                    \
    STAGE(sB1 + (kt) * 64, Bs + _d + 4096); } while (0)
#define LD_A(kk) do { const u16* _p = As + (kt & 1) * 16384 + aOff + ((kk) ? kx1 : kx0); \
    af[0] = *(const short8*)(_p);        af[1] = *(const short8*)(_p + 1024);            \
    af[2] = *(const short8*)(_p + 2048); af[3] = *(const short8*)(_p + 3072); } while (0)
#define LD_B2(kk, nh) do { const u16* _p = Bs + (kt % 3) * 8192 + bOff + ((kk) ? kx1 : kx0) + (nh) * 2048; \
    bf[(nh) * 2] = *(const short8*)(_p); bf[(nh) * 2 + 1] = *(const short8*)(_p + 1024); } while (0)
#define MFMA8(nh) do {                                                   \
    __builtin_amdgcn_s_setprio(1);                                       \
    _Pragma("unroll") for (int m = 0; m < 4; ++m) {                      \
      acc[m][(nh)*2]   = __builtin_amdgcn_mfma_f32_16x16x32_bf16(af[m], bf[(nh)*2],   acc[m][(nh)*2],   0, 0, 0); \
      acc[m][(nh)*2+1] = __builtin_amdgcn_mfma_f32_16x16x32_bf16(af[m], bf[(nh)*2+1], acc[m][(nh)*2+1], 0, 0, 0); \
    }                                                                    \
    __builtin_amdgcn_s_setprio(0); } while (0)
#define BAR __builtin_amdgcn_s_barrier()
#define WLG do { asm volatile("s_waitcnt lgkmcnt(0)" ::: "memory"); \
                 __builtin_amdgcn_sched_barrier(0); } while (0)

#define GEMM_PIPE(NKT)                                                   \
  STAGE_B(0); STAGE_A(0); STAGE_B(1);                                    \
  asm volatile("s_waitcnt vmcnt(2)" ::: "memory");                       \
  BAR;                                                                   \
  for (int kt = 0; kt < (NKT); ++kt) {                                   \
    LD_A(0); LD_B2(0, 0);                                                \
    if (kt + 1 < (NKT)) STAGE_A(kt + 1);                                 \
    BAR; WLG; MFMA8(0); BAR;                                             \
    LD_B2(0, 1);                                                         \
    BAR; WLG; MFMA8(1); BAR;                                             \
    LD_A(1); LD_B2(1, 0);                                                \
    if (kt + 2 < (NKT)) STAGE_B(kt + 2);                                 \
    BAR; WLG; MFMA8(0); BAR;                                             \
    LD_B2(1, 1);                                                         \
    BAR; WLG; MFMA8(1);                                                  \
    if (kt + 1 < (NKT)) {                                                \
      if (kt + 2 < (NKT)) { asm volatile("s_waitcnt vmcnt(2)" ::: "memory"); } \
      else                { asm volatile("s_waitcnt vmcnt(0)" ::: "memory"); } \
    }                                                                    \
    BAR;                                                                 \
  }

// ---------------- GEMM1: act[slot] = silu(g)*u  (unscaled; A gathered) ----------
__global__ __launch_bounds__(512) void k_gemm_gu(
    const u16* __restrict__ xb,     // [T][H] bf16
    const u16* __restrict__ wgupT,  // [NE][1024][H] bf16 (B^T, gate/up interleaved)
    const int* __restrict__ seg, const int* __restrict__ segcnt,
    const int* __restrict__ btok,
    u16* __restrict__ act)          // [NSLOT][ISZ] bf16
{
  const int bid = blockIdx.x;
  const int brow = (bid % NROWB) * BM;
  const int bcol = (bid / NROWB) * BN;
  int e;
  if (!seg_lookup(seg, segcnt, brow, e)) return;

  __shared__ __align__(16) u16 As[2 * 16384];   // 64 KB
  __shared__ __align__(16) u16 Bs[3 * 8192];    // 48 KB

  const int tid = threadIdx.x;
  const int w = tid >> 6, l = tid & 63;
  const int wm = w >> 1, wn = w & 1;
  const int fr = l & 15, fg = l >> 4;

  // staging geometry: round j covers tile rows j*64 + w*8 + (l>>3), chunk l&7,
  // source pre-swizzled: chunk ^= (l>>3)  (== row&7)
  const int rr = w * 8 + (l >> 3);
  const int swzc = ((l & 7) ^ (l >> 3)) * 8;
  int trow[4];
#pragma unroll
  for (int j = 0; j < 4; ++j) {
    const int gr = brow + j * 64 + rr;
    trow[j] = (e < 8) ? btok[gr] : (gr - RBASE);
  }
  const u16* sA0 = xb + (size_t)trow[0] * HID + swzc;
  const u16* sA1 = xb + (size_t)trow[1] * HID + swzc;
  const u16* sA2 = xb + (size_t)trow[2] * HID + swzc;
  const u16* sA3 = xb + (size_t)trow[3] * HID + swzc;
  const u16* sB0 = wgupT + ((size_t)e * 1024 + bcol + 0 * 64 + rr) * HID + swzc;
  const u16* sB1 = wgupT + ((size_t)e * 1024 + bcol + 1 * 64 + rr) * HID + swzc;

  // read geometry
  const int aOff = wm * 4096 + fr * 64;
  const int bOff = wn * 4096 + fr * 64;
  const int kx0 = ((fg) ^ (fr & 7)) * 8;
  const int kx1 = kx0 ^ 32;

  f32x4 acc[4][4];
#pragma unroll
  for (int m = 0; m < 4; ++m)
#pragma unroll
    for (int n = 0; n < 4; ++n) acc[m][n] = (f32x4){0.f, 0.f, 0.f, 0.f};
  short8 af[4], bf[4];

  GEMM_PIPE(HID / BK)   // 16 K-steps

  // epilogue: n pairs (2p, 2p+1) = (gate, up) 16-col fragments
#pragma unroll
  for (int m = 0; m < 4; ++m) {
#pragma unroll
    for (int p = 0; p < 2; ++p) {
      f32x4 g = acc[m][2 * p], u = acc[m][2 * p + 1];
      const int col = ((bcol + wn * 64) >> 1) + p * 16 + fr;
#pragma unroll
      for (int r = 0; r < 4; ++r) {
        const int row_l = wm * 64 + m * 16 + fg * 4 + r;
        float gate = g[r];
        float sv = gate / (1.f + __expf(-gate));
        act[(size_t)(brow + row_l) * ISZ + col] = f2bf(sv * u[r]);
      }
    }
  }
}

// ---------------- GEMM2: tmp[slot] = act[slot] @ wdT[e]  (unscaled) -------------
__global__ __launch_bounds__(512) void k_gemm_down(
    const u16* __restrict__ act, const u16* __restrict__ wdT,
    const int* __restrict__ seg, const int* __restrict__ segcnt,
    u16* __restrict__ tmp) {
  const int bid = blockIdx.x;
  const int brow = (bid % NROWB) * BM;
  const int bcol = (bid / NROWB) * BN;
  int e;
  if (!seg_lookup(seg, segcnt, brow, e)) return;

  __shared__ __align__(16) u16 As[2 * 16384];
  __shared__ __align__(16) u16 Bs[3 * 8192];

  const int tid = threadIdx.x;
  const int w = tid >> 6, l = tid & 63;
  const int wm = w >> 1, wn = w & 1;
  const int fr = l & 15, fg = l >> 4;

  const int rr = w * 8 + (l >> 3);
  const int swzc = ((l & 7) ^ (l >> 3)) * 8;
  const u16* sA0 = act + (size_t)(brow + 0 * 64 + rr) * ISZ + swzc;
  const u16* sA1 = act + (size_t)(brow + 1 * 64 + rr) * ISZ + swzc;
  const u16* sA2 = act + (size_t)(brow + 2 * 64 + rr) * ISZ + swzc;
  const u16* sA3 = act + (size_t)(brow + 3 * 64 + rr) * ISZ + swzc;
  const u16* sB0 = wdT + ((size_t)e * 1024 + bcol + 0 * 64 + rr) * ISZ + swzc;
  const u16* sB1 = wdT + ((size_t)e * 1024 + bcol + 1 * 64 + rr) * ISZ + swzc;

  const int aOff = wm * 4096 + fr * 64;
  const int bOff = wn * 4096 + fr * 64;
  const int kx0 = ((fg) ^ (fr & 7)) * 8;
  const int kx1 = kx0 ^ 32;

  f32x4 acc[4][4];
#pragma unroll
  for (int m = 0; m < 4; ++m)
#pragma unroll
    for (int n = 0; n < 4; ++n) acc[m][n] = (f32x4){0.f, 0.f, 0.f, 0.f};
  short8 af[4], bf[4];

  GEMM_PIPE(ISZ / BK)   // 8 K-steps

#pragma unroll
  for (int m = 0; m < 4; ++m) {
#pragma unroll
    for (int r = 0; r < 4; ++r) {
      const int row = brow + wm * 64 + m * 16 + fg * 4 + r;
#pragma unroll
      for (int n = 0; n < 4; ++n) {
        const int col = bcol + wn * 64 + n * 16 + fr;
        tmp[(size_t)row * HID + col] = f2bf(acc[m][n][r]);
      }
    }
  }
}

// ---------------- combine: out[t] = tmp[sh] + w0*tmp[s0] + w1*tmp[s1] -----------
__global__ __launch_bounds__(256) void k_combine(
    const u16* __restrict__ tmp, const int* __restrict__ slotmap,
    const float2* __restrict__ wts, float* __restrict__ out) {
  const int idx = blockIdx.x * 256 + threadIdx.x;
  const int t = idx >> 7;
  const int c = (idx & 127) << 3;
  const int s0 = slotmap[2 * t], s1 = slotmap[2 * t + 1];
  const float2 wv = wts[t];
  const short8 a = *(const short8*)(tmp + (size_t)s0 * HID + c);
  const short8 b = *(const short8*)(tmp + (size_t)s1 * HID + c);
  const short8 s = *(const short8*)(tmp + (size_t)(RBASE + t) * HID + c);
  float r[8];
#pragma unroll
  for (int j = 0; j < 8; ++j)
    r[j] = bf2f((u16)s[j]) + wv.x * bf2f((u16)a[j]) + wv.y * bf2f((u16)b[j]);
  float* po = out + (size_t)t * HID + c;
  *(float4*)po       = make_float4(r[0], r[1], r[2], r[3]);
  *(float4*)(po + 4) = make_float4(r[4], r[5], r[6], r[7]);
}

// ---------------- launch ----------------
extern "C" void kernel_launch(void* const* d_in, const int* in_sizes, int n_in,
                              void* d_out, int out_size, void* d_ws, size_t ws_size,
                              hipStream_t stream) {
  const float* x   = (const float*)d_in[0];
  const float* wg  = (const float*)d_in[1];
  const float* wgu = (const float*)d_in[2];
  const float* wdn = (const float*)d_in[3];
  const float* wsg = (const float*)d_in[4];
  const float* wsd = (const float*)d_in[5];
  float* out = (float*)d_out;

  char* ws = (char*)d_ws;
  u16* xb    = (u16*)ws;  ws += (size_t)T_TOK * HID * 2;
  u16* wgupT = (u16*)ws;  ws += (size_t)NE * 1024 * HID * 2;
  u16* wdT   = (u16*)ws;  ws += (size_t)NE * HID * ISZ * 2;
  u16* actb  = (u16*)ws;  ws += (size_t)NSLOT * ISZ * 2;
  u16* tmp   = (u16*)ws;  ws += (size_t)NSLOT * HID * 2;
  int* eidx  = (int*)ws;  ws += (size_t)T_TOK * 4;
  float2* wt = (float2*)ws; ws += (size_t)T_TOK * 8;
  int* btok  = (int*)ws;  ws += (size_t)RBASE * 4;
  int* smap  = (int*)ws;  ws += (size_t)2 * T_TOK * 4;
  int* seg   = (int*)ws;  ws += 16 * 4;
  int* segc  = (int*)ws;

  k_cvt_wgup<<<dim3(32, 32, NE), dim3(32, 8), 0, stream>>>(wgu, wsg, wgupT);
  k_cvt_wdown<<<dim3(32, 16, NE), dim3(32, 8), 0, stream>>>(wdn, wsd, wdT);
  k_router<<<T_TOK / 4, 256, 0, stream>>>(x, wg, xb, eidx, wt);
  k_scatter<<<1, 512, 0, stream>>>(eidx, btok, smap, seg, segc);
  k_gemm_gu<<<NROWB * (HID / BN), 512, 0, stream>>>(
      xb, wgupT, seg, segc, btok, actb);
  k_gemm_down<<<NROWB * (HID / BN), 512, 0, stream>>>(actb, wdT, seg, segc, tmp);
  k_combine<<<(T_TOK * HID / 8) / 256, 256, 0, stream>>>(tmp, smap, wt, out);
}

// Round 10
// 232.681 us; speedup vs baseline: 1.2829x; 1.0590x over previous
//
#include <hip/hip_runtime.h>
#include <hip/hip_bf16.h>
#include <cstdint>

#define T_TOK 8192
#define HID   1024
#define NE    9      // 8 routed experts + 1 shared
#define ISZ   512
#define RBASE 18432  // routed slots: 16384 + 8*256 pad; shared rows at [RBASE, RBASE+8192)
#define NSLOT (RBASE + T_TOK)   // 26624

#define BM 256
#define BN 256
#define BK 32
#define NROWB (NSLOT / BM)      // 104

typedef unsigned short u16;
typedef unsigned int   u32;
typedef __attribute__((ext_vector_type(8))) short short8;
typedef __attribute__((ext_vector_type(4))) float f32x4;

__device__ __forceinline__ u16 f2bf(float f) {
  u32 u = __builtin_bit_cast(u32, f);
  return (u16)((u + 0x7fffu + ((u >> 16) & 1u)) >> 16);
}
__device__ __forceinline__ float bf2f(u16 v) {
  return __builtin_bit_cast(float, (u32)v << 16);
}

#define STAGE(gp, lp) __builtin_amdgcn_global_load_lds( \
    (__attribute__((address_space(1))) u32*)(gp),       \
    (__attribute__((address_space(3))) u32*)(lp), 16, 0, 0)

// ---------------- k_prep: cvt_wgup + cvt_wdown + router in ONE launch ----------
#define NB_WGUP (32 * 32 * NE)   // 9216
#define NB_WDN  (32 * 16 * NE)   // 4608
#define NB_RTR  (T_TOK / 4)      // 2048

__global__ __launch_bounds__(256) void k_prep(
    const float* __restrict__ x, const float* __restrict__ wg,
    const float* __restrict__ wgu, const float* __restrict__ wsg,
    const float* __restrict__ wdn, const float* __restrict__ wsd,
    u16* __restrict__ xb, u16* __restrict__ wgupT, u16* __restrict__ wdT,
    int* __restrict__ eidx, float2* __restrict__ wts) {
  __shared__ float tile[32][33];
  const int b = blockIdx.x;
  const int tid = threadIdx.x;

  if (b < NB_WGUP) {
    // w_experts_gate_up [8][1024][1024] + shared -> [9][colp][h], gate/up 16-interleave
    const int e = b / 1024, rem = b % 1024;
    const int c0 = (rem & 31) * 32, h0 = (rem >> 5) * 32;
    const float* src = (e < 8) ? (wgu + (size_t)e * HID * 1024) : wsg;
    const int tx = tid & 31, ty = tid >> 5;
    for (int i = ty; i < 32; i += 8)
      tile[i][tx] = src[(size_t)(h0 + i) * 1024 + c0 + tx];
    __syncthreads();
    for (int j = ty; j < 32; j += 8) {
      int c = c0 + j;
      int i = (c < 512) ? c : (c - 512);
      int colp = ((i >> 4) * 32) + ((c < 512) ? 0 : 16) + (i & 15);
      wgupT[((size_t)e * 1024 + colp) * HID + h0 + tx] = f2bf(tile[tx][j]);
    }
    return;
  }
  if (b < NB_WGUP + NB_WDN) {
    const int bb = b - NB_WGUP;
    const int e = bb / 512, rem = bb % 512;
    const int h0 = (rem & 31) * 32, i0 = (rem >> 5) * 32;
    const float* src = (e < 8) ? (wdn + (size_t)e * ISZ * HID) : wsd;
    const int tx = tid & 31, ty = tid >> 5;
    for (int a = ty; a < 32; a += 8)
      tile[a][tx] = src[(size_t)(i0 + a) * HID + h0 + tx];
    __syncthreads();
    for (int j = ty; j < 32; j += 8)
      wdT[((size_t)e * HID + h0 + j) * ISZ + i0 + tx] = f2bf(tile[tx][j]);
    return;
  }
  // router: 4 tokens per block, fused x->bf16
  const int t = (b - NB_WGUP - NB_WDN) * 4 + (tid >> 6);
  const int l = tid & 63;
  float a[8] = {0, 0, 0, 0, 0, 0, 0, 0};
  const float4* xr4 = (const float4*)(x + (size_t)t * HID);
  ushort4* xb4 = (ushort4*)(xb + (size_t)t * HID);
#pragma unroll
  for (int j = 0; j < 4; ++j) {
    const float4 v = xr4[j * 64 + l];
    ushort4 o;
    o.x = f2bf(v.x); o.y = f2bf(v.y); o.z = f2bf(v.z); o.w = f2bf(v.w);
    xb4[j * 64 + l] = o;
    const int h = (j * 64 + l) * 4;
    const float ev[4] = {v.x, v.y, v.z, v.w};
#pragma unroll
    for (int i = 0; i < 4; ++i) {
      const float4 w0 = *(const float4*)&wg[(h + i) * 8];
      const float4 w1 = *(const float4*)&wg[(h + i) * 8 + 4];
      a[0] += ev[i] * w0.x; a[1] += ev[i] * w0.y; a[2] += ev[i] * w0.z; a[3] += ev[i] * w0.w;
      a[4] += ev[i] * w1.x; a[5] += ev[i] * w1.y; a[6] += ev[i] * w1.z; a[7] += ev[i] * w1.w;
    }
  }
#pragma unroll
  for (int off = 32; off >= 1; off >>= 1) {
#pragma unroll
    for (int e2 = 0; e2 < 8; ++e2) a[e2] += __shfl_xor(a[e2], off);
  }
  if (l == 0) {
    int ia = 0;
#pragma unroll
    for (int e2 = 1; e2 < 8; ++e2) if (a[e2] > a[ia]) ia = e2;
    int ib = (ia == 0) ? 1 : 0;
#pragma unroll
    for (int e2 = 0; e2 < 8; ++e2) if (e2 != ia && a[e2] > a[ib]) ib = e2;
    float wa = 1.f / (1.f + expf(a[ib] - a[ia]));
    eidx[t] = ia | (ib << 8);
    wts[t] = make_float2(wa, 1.f - wa);
  }
}

// ---------------- deterministic counting scatter (256-aligned segments) --------
__global__ __launch_bounds__(512) void k_scatter(
    const int* __restrict__ eidx, int* __restrict__ btok, int* __restrict__ slotmap,
    int* __restrict__ seg, int* __restrict__ segcnt) {
  __shared__ int cnt_s[8];
  __shared__ int goff_s[9];
  const int e = threadIdx.x >> 6;
  const int l = threadIdx.x & 63;

  int c1 = 0;
  for (int c = 0; c < T_TOK / 64; ++c) {
    int v = eidx[c * 64 + l];
    c1 += __popcll(__ballot((v & 255) == e)) + __popcll(__ballot(((v >> 8) & 255) == e));
  }
  if (l == 0) cnt_s[e] = c1;
  __syncthreads();
  if (threadIdx.x == 0) {
    int off = 0;
    for (int k = 0; k < 8; ++k) { goff_s[k] = off; off += (cnt_s[k] + 255) & ~255; }
    goff_s[8] = off;
  }
  __syncthreads();
  const int base0 = goff_s[e];
  const int cnt_e = cnt_s[e];
  const unsigned long long below = (l == 63) ? ~0ull >> 1 : ((1ull << l) - 1);

  int base = base0;
  for (int c = 0; c < T_TOK / 64; ++c) {
    const int t = c * 64 + l;
    const int v = eidx[t];
    const unsigned long long ma = __ballot((v & 255) == e);
    const unsigned long long mb = __ballot(((v >> 8) & 255) == e);
    if ((v & 255) == e) {
      int s = base + __popcll(ma & below);
      btok[s] = t; slotmap[2 * t] = s;
    }
    if (((v >> 8) & 255) == e) {
      int s = base + __popcll(ma) + __popcll(mb & below);
      btok[s] = t; slotmap[2 * t + 1] = s;
    }
    base += __popcll(ma) + __popcll(mb);
  }
  for (int p = cnt_e + l; p < ((cnt_e + 255) & ~255); p += 64) btok[base0 + p] = 0;
  if (threadIdx.x < 9) seg[threadIdx.x] = goff_s[threadIdx.x];
  if (threadIdx.x < 8) segcnt[threadIdx.x] = cnt_s[threadIdx.x];
}

__device__ __forceinline__ bool seg_lookup(const int* __restrict__ seg,
                                           const int* __restrict__ segcnt,
                                           int brow, int& e) {
  if (brow >= RBASE) { e = 8; return true; }
  if (brow >= seg[8]) return false;
  e = 0;
#pragma unroll
  for (int k = 1; k < 8; ++k) if (brow >= seg[k]) e = k;
  return brow < seg[e] + segcnt[e];
}

// =================================================================================
// 256x256 tile, BK=32, 8 waves as 2M x 4N (per-wave 128x64, acc[8][4]).
// LDS: 3-ring per operand (3 x 16 KB each = 96 KB). Stage K-tile kt+2 during kt;
// end-of-K-tile waitcnt vmcnt(4) (K+2's 4 loads stay in flight; never 0 mid-loop).
// 2 phases per K-tile, 16 MFMA per phase. Chunk swizzle q ^= row&3 both sides.
// =================================================================================

#define STG_A(kt) do { const int _d = ((kt) % 3) * 8192 + w * 1024; \
    STAGE(sA0 + (kt) * BK, As + _d);                                \
    STAGE(sA1 + (kt) * BK, As + _d + 512); } while (0)
#define STG_B(kt) do { const int _d = ((kt) % 3) * 8192 + w * 1024; \
    STAGE(sB0 + (kt) * BK, Bs + _d);                                \
    STAGE(sB1 + (kt) * BK, Bs + _d + 512); } while (0)
#define LDA4(sl, mb) do {                                            \
    af[0] = *(const short8*)&As[(sl) + aOff + ((mb) + 0) * 512];     \
    af[1] = *(const short8*)&As[(sl) + aOff + ((mb) + 1) * 512];     \
    af[2] = *(const short8*)&As[(sl) + aOff + ((mb) + 2) * 512];     \
    af[3] = *(const short8*)&As[(sl) + aOff + ((mb) + 3) * 512]; } while (0)
#define LDB4(sl) do {                                                \
    bf[0] = *(const short8*)&Bs[(sl) + bOff + 0 * 512];              \
    bf[1] = *(const short8*)&Bs[(sl) + bOff + 1 * 512];              \
    bf[2] = *(const short8*)&Bs[(sl) + bOff + 2 * 512];              \
    bf[3] = *(const short8*)&Bs[(sl) + bOff + 3 * 512]; } while (0)
#define MFMA16(mb) do { __builtin_amdgcn_s_setprio(1);               \
    _Pragma("unroll") for (int mm = 0; mm < 4; ++mm)                 \
      _Pragma("unroll") for (int nn = 0; nn < 4; ++nn)               \
        acc[(mb) + mm][nn] = __builtin_amdgcn_mfma_f32_16x16x32_bf16(\
            af[mm], bf[nn], acc[(mb) + mm][nn], 0, 0, 0);            \
    __builtin_amdgcn_s_setprio(0); } while (0)
#define BAR __builtin_amdgcn_s_barrier()
#define WLG do { asm volatile("s_waitcnt lgkmcnt(0)" ::: "memory"); \
                 __builtin_amdgcn_sched_barrier(0); } while (0)

#define GEMM_PIPE(NKT)                                               \
  STG_A(0); STG_B(0); STG_A(1); STG_B(1);                            \
  asm volatile("s_waitcnt vmcnt(4)" ::: "memory");                   \
  BAR;                                                               \
  for (int kt = 0; kt < (NKT); ++kt) {                               \
    const int sl = (kt % 3) * 8192;                                  \
    LDA4(sl, 0); LDB4(sl);                                           \
    if (kt + 2 < (NKT)) STG_A(kt + 2);                               \
    BAR; WLG; MFMA16(0); BAR;                                        \
    LDA4(sl, 4);                                                     \
    if (kt + 2 < (NKT)) STG_B(kt + 2);                               \
    BAR; WLG; MFMA16(4);                                             \
    if (kt + 2 < (NKT))      { asm volatile("s_waitcnt vmcnt(4)" ::: "memory"); } \
    else if (kt + 1 < (NKT)) { asm volatile("s_waitcnt vmcnt(0)" ::: "memory"); } \
    BAR;                                                             \
  }

// ---------------- GEMM1: act[slot] = silu(g)*u  (A gathered by token) -----------
__global__ __launch_bounds__(512) void k_gemm_gu(
    const u16* __restrict__ xb,     // [T][H] bf16
    const u16* __restrict__ wgupT,  // [NE][1024][H] bf16 (B^T, gate/up interleaved)
    const int* __restrict__ seg, const int* __restrict__ segcnt,
    const int* __restrict__ btok,
    u16* __restrict__ act)          // [NSLOT][ISZ] bf16
{
  const int brow = blockIdx.x * BM;
  const int bcol = blockIdx.y * BN;
  int e;
  if (!seg_lookup(seg, segcnt, brow, e)) return;

  __shared__ __align__(16) u16 As[3 * 8192];   // 48 KB
  __shared__ __align__(16) u16 Bs[3 * 8192];   // 48 KB

  const int tid = threadIdx.x;
  const int w = tid >> 6, l = tid & 63;
  const int wm = w >> 2, wn = w & 3;           // 2M x 4N
  const int fr = l & 15, fg = l >> 4;

  // staging: instr j covers flat = w*128 + j*64 + l -> row = flat>>2, chunk = l&3
  const int arow0 = (w * 128 + l) >> 2;        // j=0 row; j=1 row = arow0+16
  const int sw = ((l & 3) ^ (arow0 & 3)) * 8;  // pre-swizzled source chunk (elems)
  int tA0, tA1;
  if (e < 8) { tA0 = btok[brow + arow0]; tA1 = btok[brow + arow0 + 16]; }
  else       { tA0 = brow + arow0 - RBASE; tA1 = tA0 + 16; }
  const u16* sA0 = xb + (size_t)tA0 * HID + sw;
  const u16* sA1 = xb + (size_t)tA1 * HID + sw;
  const u16* sB0 = wgupT + ((size_t)e * 1024 + bcol + arow0) * HID + sw;
  const u16* sB1 = wgupT + ((size_t)e * 1024 + bcol + arow0 + 16) * HID + sw;

  // read offsets (swizzled): row stride 32 elems
  const int aOff = (wm * 128 + fr) * 32 + ((fg ^ (fr & 3)) * 8);
  const int bOff = (wn * 64 + fr) * 32 + ((fg ^ (fr & 3)) * 8);

  f32x4 acc[8][4];
#pragma unroll
  for (int m = 0; m < 8; ++m)
#pragma unroll
    for (int n = 0; n < 4; ++n) acc[m][n] = (f32x4){0.f, 0.f, 0.f, 0.f};
  short8 af[4], bf[4];

  GEMM_PIPE(HID / BK)   // 32 K-tiles

  // epilogue: n pairs (2p, 2p+1) = (gate, up) 16-col fragments
#pragma unroll
  for (int m = 0; m < 8; ++m) {
#pragma unroll
    for (int p = 0; p < 2; ++p) {
      f32x4 g = acc[m][2 * p], u = acc[m][2 * p + 1];
      const int col = ((bcol + wn * 64) >> 1) + p * 16 + fr;
#pragma unroll
      for (int r = 0; r < 4; ++r) {
        const int row_l = wm * 128 + m * 16 + fg * 4 + r;
        float gate = g[r];
        float sv = gate / (1.f + __expf(-gate));
        act[(size_t)(brow + row_l) * ISZ + col] = f2bf(sv * u[r]);
      }
    }
  }
}

// ---------------- GEMM2: tmp[slot] = act[slot] @ wdT[e] -------------------------
__global__ __launch_bounds__(512) void k_gemm_down(
    const u16* __restrict__ act, const u16* __restrict__ wdT,
    const int* __restrict__ seg, const int* __restrict__ segcnt,
    u16* __restrict__ tmp) {
  const int brow = blockIdx.x * BM;
  const int bcol = blockIdx.y * BN;
  int e;
  if (!seg_lookup(seg, segcnt, brow, e)) return;

  __shared__ __align__(16) u16 As[3 * 8192];
  __shared__ __align__(16) u16 Bs[3 * 8192];

  const int tid = threadIdx.x;
  const int w = tid >> 6, l = tid & 63;
  const int wm = w >> 2, wn = w & 3;
  const int fr = l & 15, fg = l >> 4;

  const int arow0 = (w * 128 + l) >> 2;
  const int sw = ((l & 3) ^ (arow0 & 3)) * 8;
  const u16* sA0 = act + (size_t)(brow + arow0) * ISZ + sw;
  const u16* sA1 = act + (size_t)(brow + arow0 + 16) * ISZ + sw;
  const u16* sB0 = wdT + ((size_t)e * 1024 + bcol + arow0) * ISZ + sw;
  const u16* sB1 = wdT + ((size_t)e * 1024 + bcol + arow0 + 16) * ISZ + sw;

  const int aOff = (wm * 128 + fr) * 32 + ((fg ^ (fr & 3)) * 8);
  const int bOff = (wn * 64 + fr) * 32 + ((fg ^ (fr & 3)) * 8);

  f32x4 acc[8][4];
#pragma unroll
  for (int m = 0; m < 8; ++m)
#pragma unroll
    for (int n = 0; n < 4; ++n) acc[m][n] = (f32x4){0.f, 0.f, 0.f, 0.f};
  short8 af[4], bf[4];

  GEMM_PIPE(ISZ / BK)   // 16 K-tiles

#pragma unroll
  for (int m = 0; m < 8; ++m) {
#pragma unroll
    for (int r = 0; r < 4; ++r) {
      const int row = brow + wm * 128 + m * 16 + fg * 4 + r;
#pragma unroll
      for (int n = 0; n < 4; ++n) {
        const int col = bcol + wn * 64 + n * 16 + fr;
        tmp[(size_t)row * HID + col] = f2bf(acc[m][n][r]);
      }
    }
  }
}

// ---------------- combine: out[t] = tmp[sh] + w0*tmp[s0] + w1*tmp[s1] -----------
__global__ __launch_bounds__(256) void k_combine(
    const u16* __restrict__ tmp, const int* __restrict__ slotmap,
    const float2* __restrict__ wts, float* __restrict__ out) {
  const int idx = blockIdx.x * 256 + threadIdx.x;
  const int t = idx >> 7;
  const int c = (idx & 127) << 3;
  const int s0 = slotmap[2 * t], s1 = slotmap[2 * t + 1];
  const float2 wv = wts[t];
  const short8 a = *(const short8*)(tmp + (size_t)s0 * HID + c);
  const short8 b = *(const short8*)(tmp + (size_t)s1 * HID + c);
  const short8 s = *(const short8*)(tmp + (size_t)(RBASE + t) * HID + c);
  float r[8];
#pragma unroll
  for (int j = 0; j < 8; ++j)
    r[j] = bf2f((u16)s[j]) + wv.x * bf2f((u16)a[j]) + wv.y * bf2f((u16)b[j]);
  float* po = out + (size_t)t * HID + c;
  *(float4*)po       = make_float4(r[0], r[1], r[2], r[3]);
  *(float4*)(po + 4) = make_float4(r[4], r[5], r[6], r[7]);
}

// ---------------- launch ----------------
extern "C" void kernel_launch(void* const* d_in, const int* in_sizes, int n_in,
                              void* d_out, int out_size, void* d_ws, size_t ws_size,
                              hipStream_t stream) {
  const float* x   = (const float*)d_in[0];
  const float* wg  = (const float*)d_in[1];
  const float* wgu = (const float*)d_in[2];
  const float* wdn = (const float*)d_in[3];
  const float* wsg = (const float*)d_in[4];
  const float* wsd = (const float*)d_in[5];
  float* out = (float*)d_out;

  char* ws = (char*)d_ws;
  u16* xb    = (u16*)ws;  ws += (size_t)T_TOK * HID * 2;
  u16* wgupT = (u16*)ws;  ws += (size_t)NE * 1024 * HID * 2;
  u16* wdT   = (u16*)ws;  ws += (size_t)NE * HID * ISZ * 2;
  u16* actb  = (u16*)ws;  ws += (size_t)NSLOT * ISZ * 2;
  u16* tmp   = (u16*)ws;  ws += (size_t)NSLOT * HID * 2;
  int* eidx  = (int*)ws;  ws += (size_t)T_TOK * 4;
  float2* wt = (float2*)ws; ws += (size_t)T_TOK * 8;
  int* btok  = (int*)ws;  ws += (size_t)RBASE * 4;
  int* smap  = (int*)ws;  ws += (size_t)2 * T_TOK * 4;
  int* seg   = (int*)ws;  ws += 16 * 4;
  int* segc  = (int*)ws;

  k_prep<<<NB_WGUP + NB_WDN + NB_RTR, 256, 0, stream>>>(
      x, wg, wgu, wsg, wdn, wsd, xb, wgupT, wdT, eidx, wt);
  k_scatter<<<1, 512, 0, stream>>>(eidx, btok, smap, seg, segc);
  k_gemm_gu<<<dim3(NROWB, 1024 / BN), 512, 0, stream>>>(
      xb, wgupT, seg, segc, btok, actb);
  k_gemm_down<<<dim3(NROWB, HID / BN), 512, 0, stream>>>(actb, wdT, seg, segc, tmp);
  k_combine<<<(T_TOK * HID / 8) / 256, 256, 0, stream>>>(tmp, smap, wt, out);
}